// Round 13
// baseline (1674.213 us; speedup 1.0000x reference)
//
#include <hip/hip_runtime.h>
#include <hip/hip_fp16.h>

#define NN 50000
#define NE 800000
#define INC 128
#define HIDC 64
#define NL 14
#define EPS_MSG 1e-7f
#define EPS_SM 1e-16f
#define LN_EPS 1e-5f
#define LOG2E 1.44269504088896f
#define NROW (NN + 1)          // +1 zero pad row per plane
#define SCAN_B 256
#define NB_SCAN ((NN + SCAN_B - 1) / SCAN_B)   // 196

__device__ __forceinline__ float wave_sum(float v) {
    #pragma unroll
    for (int o = 32; o > 0; o >>= 1) v += __shfl_xor(v, o, 64);
    return v;
}
__device__ __forceinline__ float wave_max(float v) {
    #pragma unroll
    for (int o = 32; o > 0; o >>= 1) v = fmaxf(v, __shfl_xor(v, o, 64));
    return v;
}
__device__ __forceinline__ float bcast(float x, int l) {
    return __int_as_float(__builtin_amdgcn_readlane(__float_as_int(x), l));
}
__device__ __forceinline__ float fexp2(float x) {
    float r; asm("v_exp_f32 %0, %1" : "=v"(r) : "v"(x)); return r;
}
__device__ __forceinline__ unsigned pk_f16(float lo, float hi) {
    unsigned r; asm("v_cvt_pkrtz_f16_f32 %0, %1, %2" : "=v"(r) : "v"(lo), "v"(hi));
    return r;
}

// ---------------- CSR build ----------------
__global__ void k_hist(const int* __restrict__ dst, int* __restrict__ deg) {
    int i = blockIdx.x * blockDim.x + threadIdx.x;
    if (i < NE) atomicAdd(&deg[dst[i]], 1);
}

__global__ void k_part(const int* __restrict__ deg, int* __restrict__ part) {
    __shared__ int sm[SCAN_B];
    int b = blockIdx.x;
    int i = b * SCAN_B + threadIdx.x;
    sm[threadIdx.x] = (i < NN) ? deg[i] : 0;
    __syncthreads();
    for (int s = SCAN_B / 2; s > 0; s >>= 1) {
        if (threadIdx.x < s) sm[threadIdx.x] += sm[threadIdx.x + s];
        __syncthreads();
    }
    if (threadIdx.x == 0) part[b] = sm[0];
}

__global__ void k_scanpart(const int* __restrict__ part, int* __restrict__ partOfs) {
    __shared__ int sm[SCAN_B];
    int t = threadIdx.x;
    int own = (t < NB_SCAN) ? part[t] : 0;
    sm[t] = own;
    __syncthreads();
    for (int o = 1; o < SCAN_B; o <<= 1) {
        int v = (t >= o) ? sm[t - o] : 0;
        __syncthreads();
        sm[t] += v;
        __syncthreads();
    }
    if (t < NB_SCAN) partOfs[t] = sm[t] - own;   // exclusive
}

__global__ void k_scanfinal(const int* __restrict__ deg, const int* __restrict__ partOfs,
                            int* __restrict__ rowOfs, int* __restrict__ rowCur) {
    __shared__ int sm[SCAN_B];
    int b = blockIdx.x, t = threadIdx.x;
    int i = b * SCAN_B + t;
    int d = (i < NN) ? deg[i] : 0;
    sm[t] = d;
    __syncthreads();
    for (int o = 1; o < SCAN_B; o <<= 1) {
        int v = (t >= o) ? sm[t - o] : 0;
        __syncthreads();
        sm[t] += v;
        __syncthreads();
    }
    if (i < NN) {
        int r = partOfs[b] + sm[t] - d;
        rowOfs[i] = r;
        rowCur[i] = r;
    }
    if (i == 0) rowOfs[NN] = NE;
}

__global__ void k_scatter(const int* __restrict__ src, const int* __restrict__ dst,
                          int* __restrict__ rowCur, unsigned short* __restrict__ csrU) {
    int i = blockIdx.x * blockDim.x + threadIdx.x;
    if (i < NE) {
        int p = atomicAdd(&rowCur[dst[i]], 1);
        csrU[p] = (unsigned short)src[i];
    }
}

// zero the pad rows (index NN) of all 4 planes of both tables
__global__ void k_zpad(unsigned* __restrict__ B0, unsigned* __restrict__ B1) {
    int i = threadIdx.x;                  // 0..127
    unsigned* B = (i < 64) ? B0 : B1;
    int j = i & 63;
    int p = j >> 4, w = j & 15;
    B[((size_t)p * NROW + NN) * 16 + w] = 0;
}

// write one node's (E,P) f16-pair table entries; lane = channel
__device__ __forceinline__ void write_ep(unsigned* __restrict__ B, int v, int lane,
                                         float y, float sc) {
    float G = sc * y;                      // y >= 0
    float E = fexp2(G);
    float P = G * E;
    float Ep = __shfl_xor(E, 1, 64);
    float Pp = __shfl_xor(P, 1, 64);
    if (!(lane & 1)) {
        unsigned we = pk_f16(E, Ep);
        unsigned wp = pk_f16(P, Pp);
        int p = lane >> 4, k = (lane & 15) >> 1;
        ((uint2*)B)[((size_t)p * NROW + v) * 8 + k] = make_uint2(we, wp);
    }
}

// ---- encoder: h = x @ encW + encb ; emits fp32 henc + (E,P) table B0
__global__ __launch_bounds__(256) void k_enc(const float* __restrict__ x,
                                             const float* __restrict__ W,
                                             const float* __restrict__ bias,
                                             const float* __restrict__ tptr,
                                             float* __restrict__ h,
                                             unsigned* __restrict__ B0) {
    __shared__ float XL[32 * INC];     // 16 KB
    __shared__ float WL[INC * HIDC];   // 32 KB
    int tid = threadIdx.x;
    for (int i = tid; i < (INC * HIDC) / 4; i += 256)
        ((float4*)WL)[i] = ((const float4*)W)[i];
    int r0 = blockIdx.x * 32;
    for (int i = tid; i < (32 * INC) / 4; i += 256) {
        int row = i >> 5;
        float4 val = make_float4(0.f, 0.f, 0.f, 0.f);
        if (r0 + row < NN) val = ((const float4*)x)[(size_t)(r0 + row) * 32 + (i & 31)];
        ((float4*)XL)[i] = val;
    }
    __syncthreads();
    int lane = tid & 63, w = tid >> 6;
    float bv = bias[lane];
    float sc = tptr[0] * LOG2E;
    #pragma unroll
    for (int i = 0; i < 4; i++) {
        int ra = w * 8 + i * 2, rb = ra + 1;
        float a0 = 0.f, a1 = 0.f, a2 = 0.f, a3 = 0.f;
        float c0 = 0.f, c1 = 0.f, c2 = 0.f, c3 = 0.f;
        #pragma unroll
        for (int k = 0; k < INC; k += 4) {
            float4 xa = *(const float4*)&XL[ra * INC + k];
            float4 xb = *(const float4*)&XL[rb * INC + k];
            float w0 = WL[(k + 0) * HIDC + lane];
            float w1 = WL[(k + 1) * HIDC + lane];
            float w2 = WL[(k + 2) * HIDC + lane];
            float w3 = WL[(k + 3) * HIDC + lane];
            a0 = fmaf(xa.x, w0, a0); a1 = fmaf(xa.y, w1, a1);
            a2 = fmaf(xa.z, w2, a2); a3 = fmaf(xa.w, w3, a3);
            c0 = fmaf(xb.x, w0, c0); c1 = fmaf(xb.y, w1, c1);
            c2 = fmaf(xb.z, w2, c2); c3 = fmaf(xb.w, w3, c3);
        }
        int ga = r0 + ra, gb = r0 + rb;
        float va = bv + ((a0 + a1) + (a2 + a3));
        float vb = bv + ((c0 + c1) + (c2 + c3));
        if (ga < NN) {
            h[(size_t)ga * HIDC + lane] = va;
            write_ep(B0, ga, lane, fmaxf(va, 0.f), sc);
        }
        if (gb < NN) {
            h[(size_t)gb * HIDC + lane] = vb;
            write_ep(B0, gb, lane, fmaxf(vb, 0.f), sc);
        }
    }
}

// ---- phase A: gather-sum aggregation over precomputed (E,P).
// grid (12500, 4): blockIdx.y = plane (16 ch). wave = one node.
// lanes: 16 edge-subgroups x 4 chunks; uint4 = 4 ch of (E,P) pairs = 64B row/4.
template<bool FIRST>
__global__ __launch_bounds__(256) void k_aggr(const float* __restrict__ henc,
                                              const unsigned* __restrict__ Bin,
                                              const int* __restrict__ rowOfs,
                                              const unsigned short* __restrict__ csrU,
                                              const float* __restrict__ tptr,
                                              float* __restrict__ A) {
    int lane = threadIdx.x & 63;
    int v = blockIdx.x * 4 + (threadIdx.x >> 6);
    int p = blockIdx.y;
    int eg = lane >> 2;        // edge subgroup 0..15
    int q = lane & 3;          // 16B chunk -> channels 4q..4q+3 of plane
    const uint4* base = (const uint4*)(Bin + (size_t)p * NROW * 16);
    float invs = 1.0f / (tptr[0] * LOG2E);

    int e0 = rowOfs[v], e1 = rowOfs[v + 1];
    float se0 = 0.f, se1 = 0.f, se2 = 0.f, se3 = 0.f;
    float sw0 = 0.f, sw1 = 0.f, sw2 = 0.f, sw3 = 0.f;
    for (int e = e0; e < e1; e += 16) {
        int ee = e + eg;
        int idx = (ee < e1) ? (int)__builtin_nontemporal_load(csrU + ee) : NN;
        uint4 qd = base[(size_t)idx * 4 + q];
        __half2 E01 = *reinterpret_cast<__half2*>(&qd.x);
        __half2 P01 = *reinterpret_cast<__half2*>(&qd.y);
        __half2 E23 = *reinterpret_cast<__half2*>(&qd.z);
        __half2 P23 = *reinterpret_cast<__half2*>(&qd.w);
        se0 += __low2float(E01); se1 += __high2float(E01);
        sw0 += __low2float(P01); sw1 += __high2float(P01);
        se2 += __low2float(E23); se3 += __high2float(E23);
        sw2 += __low2float(P23); sw3 += __high2float(P23);
    }
    // reduce across the 16 edge-subgroups (chunk q preserved)
    #pragma unroll
    for (int m = 4; m <= 32; m <<= 1) {
        se0 += __shfl_xor(se0, m, 64); sw0 += __shfl_xor(sw0, m, 64);
        se1 += __shfl_xor(se1, m, 64); sw1 += __shfl_xor(sw1, m, 64);
        se2 += __shfl_xor(se2, m, 64); sw2 += __shfl_xor(sw2, m, 64);
        se3 += __shfl_xor(se3, m, 64); sw3 += __shfl_xor(sw3, m, 64);
    }
    if (lane < 4) {            // eg == 0, q = lane
        float4 r;
        r.x = sw0 / (se0 + EPS_SM) * invs + EPS_MSG;
        r.y = sw1 / (se1 + EPS_SM) * invs + EPS_MSG;
        r.z = sw2 / (se2 + EPS_SM) * invs + EPS_MSG;
        r.w = sw3 / (se3 + EPS_SM) * invs + EPS_MSG;
        if (FIRST) {
            float4 s4 = ((const float4*)henc)[(size_t)v * 16 + p * 4 + lane];
            r.x += s4.x; r.y += s4.y; r.z += s4.z; r.w += s4.w;
        }
        ((float4*)A)[(size_t)v * 16 + p * 4 + lane] = r;
    }
}

// ---- phase B: dense MLP row kernel. grid-stride, W staged once per block.
template<bool LNRES, int MODE>
__global__ __launch_bounds__(256) void k_mlp(const float* __restrict__ A,
                                             float* __restrict__ h,
                                             unsigned* __restrict__ Bout,
                                             const float* __restrict__ W,
                                             const float* __restrict__ b,
                                             const float* __restrict__ tnext) {
    __shared__ float WL[HIDC * HIDC];  // 16 KB
    for (int i = threadIdx.x; i < (HIDC * HIDC) / 4; i += 256)
        ((float4*)WL)[i] = ((const float4*)W)[i];
    __syncthreads();

    int lane = threadIdx.x & 63;
    int wid = (blockIdx.x * 256 + threadIdx.x) >> 6;
    int nw = (gridDim.x * 256) >> 6;
    float bv = b[lane];
    float sc = (MODE == 0) ? tnext[0] * LOG2E : 0.f;

    for (int v = wid; v < NN; v += nw) {
        float a = A[(size_t)v * HIDC + lane];
        float base = bv;
        if (LNRES) {
            float hv = h[(size_t)v * HIDC + lane];
            float mu = wave_sum(hv) * (1.f / 64.f);
            float d = hv - mu;
            float var = wave_sum(d * d) * (1.f / 64.f);
            a += fmaxf(d * rsqrtf(var + LN_EPS), 0.f);
            base += hv;
        }
        float a0 = 0.f, a1 = 0.f, a2 = 0.f, a3 = 0.f;
        #pragma unroll
        for (int k = 0; k < 64; k += 4) {
            a0 = fmaf(bcast(a, k + 0), WL[(k + 0) * HIDC + lane], a0);
            a1 = fmaf(bcast(a, k + 1), WL[(k + 1) * HIDC + lane], a1);
            a2 = fmaf(bcast(a, k + 2), WL[(k + 2) * HIDC + lane], a2);
            a3 = fmaf(bcast(a, k + 3), WL[(k + 3) * HIDC + lane], a3);
        }
        float acc = base + ((a0 + a1) + (a2 + a3));

        if (MODE == 1) {
            float mu = wave_sum(acc) * (1.f / 64.f);
            float d = acc - mu;
            float var = wave_sum(d * d) * (1.f / 64.f);
            float z = fmaxf(d * rsqrtf(var + LN_EPS), 0.f);
            float m = wave_max(z);
            float s2 = wave_sum(fexp2((z - m) * LOG2E));
            h[(size_t)v * HIDC + lane] = z - (m + __logf(s2));
        } else {
            h[(size_t)v * HIDC + lane] = acc;
            float mu = wave_sum(acc) * (1.f / 64.f);
            float d = acc - mu;
            float var = wave_sum(d * d) * (1.f / 64.f);
            float y = fmaxf(d * rsqrtf(var + LN_EPS), 0.f);
            write_ep(Bout, v, lane, y, sc);
        }
    }
}

extern "C" void kernel_launch(void* const* d_in, const int* in_sizes, int n_in,
                              void* d_out, int out_size, void* d_ws, size_t ws_size,
                              hipStream_t stream) {
    const float* x    = (const float*)d_in[0];
    const int*   ei   = (const int*)d_in[1];
    const float* encW = (const float*)d_in[2];
    const float* encb = (const float*)d_in[3];
    const float* mlpW = (const float*)d_in[4];
    const float* mlpb = (const float*)d_in[5];
    const float* t    = (const float*)d_in[6];

    float* h = (float*)d_out;   // residual carry, doubles as final output

    char* ws = (char*)d_ws;
    size_t off = 0;
    auto alloc = [&](size_t bytes) -> void* {
        void* p = ws + off;
        off += (bytes + 255) / 256 * 256;
        return p;
    };
    float*          henc   = (float*)alloc((size_t)NN * HIDC * 4);
    float*          A      = (float*)alloc((size_t)NN * HIDC * 4);
    unsigned*       B0     = (unsigned*)alloc((size_t)4 * NROW * 16 * 4);  // 12.8 MB
    unsigned*       B1     = (unsigned*)alloc((size_t)4 * NROW * 16 * 4);
    int*            deg    = (int*)alloc((size_t)NN * 4);
    int*            rowOfs = (int*)alloc((size_t)(NN + 1) * 4);
    int*            rowCur = (int*)alloc((size_t)NN * 4);
    int*            part   = (int*)alloc((size_t)NB_SCAN * 4);
    int*            partOf = (int*)alloc((size_t)NB_SCAN * 4);
    unsigned short* csrU   = (unsigned short*)alloc((size_t)NE * 2);

    const int* src = ei;
    const int* dst = ei + NE;

    hipMemsetAsync(deg, 0, (size_t)NN * 4, stream);

    k_hist<<<(NE + 255) / 256, 256, 0, stream>>>(dst, deg);
    k_part<<<NB_SCAN, SCAN_B, 0, stream>>>(deg, part);
    k_scanpart<<<1, SCAN_B, 0, stream>>>(part, partOf);
    k_scanfinal<<<NB_SCAN, SCAN_B, 0, stream>>>(deg, partOf, rowOfs, rowCur);
    k_scatter<<<(NE + 255) / 256, 256, 0, stream>>>(src, dst, rowCur, csrU);
    k_zpad<<<1, 128, 0, stream>>>(B0, B1);

    k_enc<<<(NN + 31) / 32, 256, 0, stream>>>(x, encW, encb, t, henc, B0);

    dim3 agrid(12500, 4);
    // layer 0
    k_aggr<true><<<agrid, 256, 0, stream>>>(henc, B0, rowOfs, csrU, t, A);
    k_mlp<false, 0><<<2048, 256, 0, stream>>>(A, h, B1, mlpW, mlpb, t + 1);

    for (int l = 1; l < NL - 1; l++) {
        unsigned* Bi = (l & 1) ? B1 : B0;
        unsigned* Bo = (l & 1) ? B0 : B1;
        k_aggr<false><<<agrid, 256, 0, stream>>>(nullptr, Bi, rowOfs, csrU, t + l, A);
        k_mlp<true, 0><<<2048, 256, 0, stream>>>(A, h, Bo,
                                                 mlpW + (size_t)l * HIDC * HIDC,
                                                 mlpb + (size_t)l * HIDC, t + l + 1);
    }
    // layer 13: final -> log_softmax into h
    k_aggr<false><<<agrid, 256, 0, stream>>>(nullptr, B1, rowOfs, csrU, t + (NL - 1), A);
    k_mlp<true, 1><<<2048, 256, 0, stream>>>(A, h, nullptr,
                                             mlpW + (size_t)(NL - 1) * HIDC * HIDC,
                                             mlpb + (size_t)(NL - 1) * HIDC, nullptr);
}